// Round 12
// baseline (253.174 us; speedup 1.0000x reference)
//
#include <hip/hip_runtime.h>
#include <hip/hip_bf16.h>
#include <math.h>

typedef __hip_bfloat16 bf16;
typedef __bf16 nbf16;
typedef __bf16 bf16x8 __attribute__((ext_vector_type(8)));
typedef __bf16 bf16x4 __attribute__((ext_vector_type(4)));
typedef float f32x4 __attribute__((ext_vector_type(4)));

#define D_MODEL 1024
#define NHEAD   16
#define HDK     64
#define BATCH   2
#define SEQ     2048
#define QSZ     ((size_t)BATCH * SEQ * D_MODEL)
#define WSZ     ((size_t)D_MODEL * D_MODEL)

// ---------------------------------------------------------------------------
// Dtype auto-detect (unchanged, proven).
// ---------------------------------------------------------------------------
__global__ void detect_dtype(const unsigned short* __restrict__ x, int* flag) {
    __shared__ int cnt;
    if (threadIdx.x == 0) cnt = 0;
    __syncthreads();
    int local = 0;
    for (int i = threadIdx.x; i < 4096; i += 256) {
        const unsigned short v = x[i];
        const int e = (v >> 7) & 0xFF;
        if (v == 0 || (e >= 96 && e <= 141)) local++;
    }
    atomicAdd(&cnt, local);
    __syncthreads();
    if (threadIdx.x == 0) *flag = (cnt >= 3600) ? 1 : 0;
}

__device__ __forceinline__ float ldIn(const void* p, size_t i, int isbf16) {
    return isbf16 ? __bfloat162float(((const bf16*)p)[i])
                  : ((const float*)p)[i];
}

__device__ __forceinline__ void gload_lds16(const void* g, void* l) {
    __builtin_amdgcn_global_load_lds(
        (const __attribute__((address_space(1))) void*)g,
        (__attribute__((address_space(3))) void*)l, 16, 0, 0);
}

// ---------------------------------------------------------------------------
// prep: fused {X,Y -> bf16} + {4x weight transpose} (proven rounds 8-11).
// ---------------------------------------------------------------------------
__global__ void prep(const void* __restrict__ X, const void* __restrict__ Y,
                     const void* __restrict__ qW, const void* __restrict__ kW,
                     const void* __restrict__ vW, const void* __restrict__ oW,
                     nbf16* __restrict__ Xb, nbf16* __restrict__ Yb,
                     nbf16* __restrict__ Wt3, nbf16* __restrict__ Wto,
                     const int* __restrict__ flagp) {
    const int flag = *flagp;
    const int id = blockIdx.x;
    if (id < 4096) {
        const bool isX = id < 2048;
        const void* in = isX ? X : Y;
        nbf16* out     = isX ? Xb : Yb;
        const size_t i = ((size_t)(isX ? id : id - 2048) * 256 +
                          threadIdx.x) * 8;
        if (flag) {
            *(uint4*)(out + i) = *(const uint4*)((const nbf16*)in + i);
        } else {
            const float4 a = *(const float4*)((const float*)in + i);
            const float4 b = *(const float4*)((const float*)in + i + 4);
            bf16x8 v = {(nbf16)a.x, (nbf16)a.y, (nbf16)a.z, (nbf16)a.w,
                        (nbf16)b.x, (nbf16)b.y, (nbf16)b.z, (nbf16)b.w};
            *(bf16x8*)(out + i) = v;
        }
    } else {
        const int t = id - 4096;
        const int z = t >> 8;
        const int tile = t & 255;
        const void* W = (z == 0) ? qW : (z == 1) ? kW : (z == 2) ? vW : oW;
        nbf16* Wt = (z == 3) ? Wto : Wt3 + (size_t)z * WSZ;

        __shared__ float T[64][65];
        const int k0 = (tile & 15) * 64, n0 = (tile >> 4) * 64;
        #pragma unroll
        for (int i = 0; i < 16; ++i) {
            const int idx = threadIdx.x + i * 256;
            const int r = idx >> 6, c = idx & 63;
            T[r][c] = ldIn(W, (size_t)(k0 + r) * D_MODEL + n0 + c, flag);
        }
        __syncthreads();
        #pragma unroll
        for (int i = 0; i < 16; ++i) {
            const int idx = threadIdx.x + i * 256;
            const int n = idx >> 6, k = idx & 63;
            Wt[(size_t)(n0 + n) * D_MODEL + k0 + k] = (nbf16)T[k][n];
        }
    }
}

// ---------------------------------------------------------------------------
// Single-buffer staging for the m97-style proj_qkv (32 KB LDS, 3 blk/CU).
// ---------------------------------------------------------------------------
#define STAGE1(Albuf, Blbuf, Aptr, Bptr, t)                                    \
{                                                                              \
    const int _k0 = (t) * 64;                                                  \
    _Pragma("unroll")                                                          \
    for (int i = 0; i < 4; ++i) {                                              \
        const int row = i * 32 + wid * 8 + (lane >> 3);                        \
        const int ss  = (lane & 7) ^ (row & 7);                                \
        gload_lds16((Aptr) + (size_t)row * D_MODEL + _k0 + ss * 8,             \
                    (nbf16*)(Albuf) + i * 2048 + wid * 512);                   \
        gload_lds16((Bptr) + (size_t)row * D_MODEL + _k0 + ss * 8,             \
                    (nbf16*)(Blbuf) + i * 2048 + wid * 512);                   \
    }                                                                          \
}

// ---------------------------------------------------------------------------
// Fused QKV projection, m97 structure (proven round 11).
// ---------------------------------------------------------------------------
__global__ __launch_bounds__(256, 3) void proj_qkv(
        const nbf16* __restrict__ Xb, const nbf16* __restrict__ Yb,
        const nbf16* __restrict__ Wt3,
        const void* __restrict__ qB, const void* __restrict__ kB,
        const void* __restrict__ vB,
        nbf16* __restrict__ outq, const int* __restrict__ flagp) {
    __shared__ nbf16 Al[128][64];   // 16 KB
    __shared__ nbf16 Bl[128][64];   // 16 KB

    const int flag = *flagp;
    const int tid  = threadIdx.x;
    const int wid  = tid >> 6;
    const int lane = tid & 63;
    const int l15  = lane & 15;
    const int lg   = lane >> 4;
    const int wr   = wid >> 1;
    const int wc   = wid & 1;

    const int id = blockIdx.x;
    const int sw = (id & 7) * 96 + (id >> 3);
    const int m0  = (sw & 31) * 128;
    const int ng0 = (sw >> 5) * 128;

    const nbf16* A  = (ng0 < D_MODEL) ? Yb : Xb;
    const nbf16* Bm = Wt3 + (size_t)ng0 * D_MODEL;
    const nbf16* Am = A + (size_t)m0 * D_MODEL;

    f32x4 acc[4][4];
    #pragma unroll
    for (int mi = 0; mi < 4; ++mi)
        #pragma unroll
        for (int ni = 0; ni < 4; ++ni) acc[mi][ni] = (f32x4){0.f, 0.f, 0.f, 0.f};

    const int NT = D_MODEL / 64;   // 16
    for (int t = 0; t < NT; ++t) {
        STAGE1(&Al[0][0], &Bl[0][0], Am, Bm, t);
        __syncthreads();
        #pragma unroll
        for (int kk = 0; kk < 2; ++kk) {
            bf16x8 af[4], bfr[4];
            #pragma unroll
            for (int mi = 0; mi < 4; ++mi) {
                const int ar = wr * 64 + mi * 16 + l15;
                const int sl = ((kk << 2) + lg) ^ (ar & 7);
                af[mi] = *(const bf16x8*)((const nbf16*)&Al[ar][0] + sl * 8);
            }
            #pragma unroll
            for (int ni = 0; ni < 4; ++ni) {
                const int br = wc * 64 + ni * 16 + l15;
                const int sl = ((kk << 2) + lg) ^ (br & 7);
                bfr[ni] = *(const bf16x8*)((const nbf16*)&Bl[br][0] + sl * 8);
            }
            #pragma unroll
            for (int mi = 0; mi < 4; ++mi)
                #pragma unroll
                for (int ni = 0; ni < 4; ++ni)
                    acc[mi][ni] = __builtin_amdgcn_mfma_f32_16x16x32_bf16(
                        af[mi], bfr[ni], acc[mi][ni], 0, 0, 0);
        }
        __syncthreads();
    }

    #pragma unroll
    for (int ni = 0; ni < 4; ++ni) {
        const int n  = ng0 + wc * 64 + ni * 16 + l15;
        const int wh = n >> 10;
        const int nl = n & 1023;
        const void* bp = (wh == 0) ? qB : (wh == 1) ? kB : vB;
        const float bias = ldIn(bp, (size_t)nl, flag);
        nbf16* outp = outq + (size_t)wh * QSZ;
        #pragma unroll
        for (int mi = 0; mi < 4; ++mi) {
            #pragma unroll
            for (int r = 0; r < 4; ++r) {
                const int m = m0 + wr * 64 + mi * 16 + lg * 4 + r;
                const float v = acc[mi][ni][r] + bias;
                const int b = m >> 11, s = m & (SEQ - 1);
                const int h = nl >> 6,  d = nl & (HDK - 1);
                outp[(((size_t)(b * NHEAD + h)) * SEQ + s) * HDK + d] = (nbf16)v;
            }
        }
    }
}

// ---------------------------------------------------------------------------
// O projection, 128x128 dbuf (proven rounds 5-11, frozen).
// ---------------------------------------------------------------------------
#define STAGE128(Albuf, Blbuf, Aptr, Bptr, t)                                  \
{                                                                              \
    const int _k0 = (t) * 64;                                                  \
    _Pragma("unroll")                                                          \
    for (int i = 0; i < 4; ++i) {                                              \
        const int row = i * 32 + wid * 8 + (lane >> 3);                        \
        const int ss  = (lane & 7) ^ (row & 7);                                \
        gload_lds16((Aptr) + (size_t)row * D_MODEL + _k0 + ss * 8,             \
                    (nbf16*)(Albuf) + i * 2048 + wid * 512);                   \
        gload_lds16((Bptr) + (size_t)row * D_MODEL + _k0 + ss * 8,             \
                    (nbf16*)(Blbuf) + i * 2048 + wid * 512);                   \
    }                                                                          \
}

__global__ __launch_bounds__(256, 2) void proj_o(
        const nbf16* __restrict__ A, const nbf16* __restrict__ Wt,
        const void* __restrict__ Braw, void* __restrict__ Cout,
        const int* __restrict__ flagp) {
    __shared__ nbf16 Al[2][128][64];
    __shared__ nbf16 Bl[2][128][64];

    const int flag = *flagp;
    const int tid  = threadIdx.x;
    const int wid  = tid >> 6;
    const int lane = tid & 63;
    const int l15  = lane & 15;
    const int lg   = lane >> 4;
    const int wr   = wid >> 1;
    const int wc   = wid & 1;

    const int id = blockIdx.x;
    const int sw = (id & 7) * 32 + (id >> 3);
    const int m0 = (sw >> 3) * 128;
    const int n0 = (sw & 7) * 128;

    const nbf16* Am = A + (size_t)m0 * D_MODEL;
    const nbf16* Bm = Wt + (size_t)n0 * D_MODEL;

    f32x4 acc[4][4];
    #pragma unroll
    for (int mi = 0; mi < 4; ++mi)
        #pragma unroll
        for (int ni = 0; ni < 4; ++ni) acc[mi][ni] = (f32x4){0.f, 0.f, 0.f, 0.f};

    STAGE128(&Al[0][0][0], &Bl[0][0][0], Am, Bm, 0);
    __syncthreads();

    const int NT = D_MODEL / 64;
    for (int t = 0; t < NT; ++t) {
        const int cur = t & 1;
        if (t + 1 < NT)
            STAGE128(&Al[cur ^ 1][0][0], &Bl[cur ^ 1][0][0], Am, Bm, t + 1);
        #pragma unroll
        for (int kk = 0; kk < 2; ++kk) {
            bf16x8 af[4], bfr[4];
            #pragma unroll
            for (int mi = 0; mi < 4; ++mi) {
                const int ar = wr * 64 + mi * 16 + l15;
                const int sl = ((kk << 2) + lg) ^ (ar & 7);
                af[mi] = *(const bf16x8*)((const nbf16*)&Al[cur][ar][0] + sl * 8);
            }
            #pragma unroll
            for (int ni = 0; ni < 4; ++ni) {
                const int br = wc * 64 + ni * 16 + l15;
                const int sl = ((kk << 2) + lg) ^ (br & 7);
                bfr[ni] = *(const bf16x8*)((const nbf16*)&Bl[cur][br][0] + sl * 8);
            }
            #pragma unroll
            for (int mi = 0; mi < 4; ++mi)
                #pragma unroll
                for (int ni = 0; ni < 4; ++ni)
                    acc[mi][ni] = __builtin_amdgcn_mfma_f32_16x16x32_bf16(
                        af[mi], bfr[ni], acc[mi][ni], 0, 0, 0);
        }
        __syncthreads();
    }

    #pragma unroll
    for (int ni = 0; ni < 4; ++ni) {
        const int n = n0 + wc * 64 + ni * 16 + l15;
        const float bias = ldIn(Braw, (size_t)n, flag);
        #pragma unroll
        for (int mi = 0; mi < 4; ++mi) {
            #pragma unroll
            for (int r = 0; r < 4; ++r) {
                const int m = m0 + wr * 64 + mi * 16 + lg * 4 + r;
                const float v = acc[mi][ni][r] + bias;
                if (flag) ((bf16*)Cout)[(size_t)m * D_MODEL + n] = __float2bfloat16(v);
                else      ((float*)Cout)[(size_t)m * D_MODEL + n] = v;
            }
        }
    }
}

// ---------------------------------------------------------------------------
// MFMA flash attention v8: PB ELIMINATED via k-slot permutation.
// MFMA sums over k; permuting k identically in A and B is exact. The swapped
// QK^T leaves lane (l15,lg) holding P[q=l15][kv = s*16+lg*4+r] -- exactly the
// A-frag slot order IF V is stored at permuted column khat(kv) (bit-swap
// [b5][b4][b3b2][b1b0] -> [b5][b3b2][b4][b1b0]; bijective, pair-adjacent,
// u32-aligned). Verified: storage col lg*8+j holds kv=(j>>2)*16+lg*4+(j&3).
// So P-frags are the lane's exp2 results packed to bf16 -- NO LDS round-trip.
// Deletes PB (16 KB -> LDS 32 KB -> 4-5 blk/CU), the lgkmcnt fence, and the
// softmax->PV serialization. Everything else = r11 (proven).
// ---------------------------------------------------------------------------
template<bool SPLIT>
__global__ __launch_bounds__(256, SPLIT ? 4 : 2) void attn_mfma(
        const nbf16* __restrict__ qg, const nbf16* __restrict__ kg,
        const nbf16* __restrict__ vg, nbf16* __restrict__ cg,
        float* __restrict__ part_o, float2* __restrict__ part_ms) {
    __shared__ nbf16 KL[2][64][64];   // 16 KB
    __shared__ nbf16 VT[2][64][64];   // 16 KB (khat-permuted + XOR-swizzled)

    const int tid  = threadIdx.x;
    const int wid  = tid >> 6;
    const int lane = tid & 63;
    const int l15  = lane & 15;
    const int lg   = lane >> 4;

    const int id = blockIdx.x;
    const int sw = SPLIT ? ((id & 7) * 128 + (id >> 3))
                         : ((id & 7) * 64 + (id >> 3));
    const int bh   = SPLIT ? (sw >> 5) : (sw >> 4);
    const int qt   = SPLIT ? ((sw & 31) >> 1) : (sw & 15);
    const int half = SPLIT ? (sw & 1) : 0;

    const nbf16* qb = qg + (size_t)bh * SEQ * HDK;
    const nbf16* kb = kg + (size_t)bh * SEQ * HDK +
                      (size_t)half * (SEQ / 2) * HDK;
    const nbf16* vb = vg + (size_t)bh * SEQ * HDK +
                      (size_t)half * (SEQ / 2) * HDK;

    const float SCf = 0.125f * 1.44269504088896340736f;

    const int qbase = qt * 128 + wid * 32;
    const nbf16* qpA = qb + (size_t)(qbase + l15) * HDK + lg * 8;
    const nbf16* qpB = qpA + 16 * HDK;
    bf16x8 qfA0 = *(const bf16x8*)qpA;
    bf16x8 qfA1 = *(const bf16x8*)(qpA + 32);
    bf16x8 qfB0 = *(const bf16x8*)qpB;
    bf16x8 qfB1 = *(const bf16x8*)(qpB + 32);
    #pragma unroll
    for (int j = 0; j < 8; ++j) {
        qfA0[j] = (nbf16)((float)qfA0[j] * SCf);
        qfA1[j] = (nbf16)((float)qfA1[j] * SCf);
        qfB0[j] = (nbf16)((float)qfB0[j] * SCf);
        qfB1[j] = (nbf16)((float)qfB1[j] * SCf);
    }

    const bf16x8 ones = {(nbf16)1.f, (nbf16)1.f, (nbf16)1.f, (nbf16)1.f,
                         (nbf16)1.f, (nbf16)1.f, (nbf16)1.f, (nbf16)1.f};

    const int g8 = (tid >> 5) * 8;
    const int p2 = (tid & 31) * 2;
    // khat(p2): [b5][b4][b3b2][b1b0] -> [b5][b3b2][b4][b1b0]
    const int kh = (p2 & 32) | ((p2 & 12) << 1) | ((p2 & 16) >> 2) | (p2 & 3);

    const int swz0 = (lg * 8)      ^ ((l15 & 7) << 3);
    const int swz1 = (lg * 8 + 32) ^ ((l15 & 7) << 3);

    #define STAGEK(buf, t)                                                     \
    {                                                                          \
        _Pragma("unroll")                                                      \
        for (int i = 0; i < 2; ++i) {                                          \
            const int row = i * 32 + wid * 8 + (lane >> 3);                    \
            const int ss  = (lane & 7) ^ (row & 7);                            \
            gload_lds16(kb + (size_t)((t) * 64 + row) * HDK + ss * 8,          \
                        (nbf16*)&KL[buf][0][0] + i * 2048 + wid * 512);        \
        }                                                                      \
    }

    #define VLOAD(t)                                                           \
        a0 = *(const uint4*)(vb + (size_t)((t) * 64 + p2) * HDK + g8);         \
        a1 = *(const uint4*)(vb + (size_t)((t) * 64 + p2 + 1) * HDK + g8);

    #define VWRITE(buf)                                                        \
    {                                                                          \
        const unsigned short* e0 = (const unsigned short*)&a0;                 \
        const unsigned short* e1 = (const unsigned short*)&a1;                 \
        _Pragma("unroll")                                                      \
        for (int j = 0; j < 8; ++j)                                            \
            *(unsigned int*)&VT[buf][g8 + j][kh ^ (j << 3)] =                  \
                (unsigned int)e0[j] | ((unsigned int)e1[j] << 16);             \
    }

    // T13 defer-max (log2 domain, THR=8); P-frags built DIRECTLY in registers.
    #define SOFTMAX(st, m2, o, osum, pf0, pf1)                                 \
    do {                                                                       \
        float tmx[4];                                                          \
        _Pragma("unroll")                                                      \
        for (int s_ = 0; s_ < 4; ++s_)                                         \
            tmx[s_] = fmaxf(fmaxf(st[s_][0], st[s_][1]),                       \
                            fmaxf(st[s_][2], st[s_][3]));                      \
        float tm = fmaxf(fmaxf(tmx[0], tmx[1]), fmaxf(tmx[2], tmx[3]));        \
        tm = fmaxf(tm, __shfl_xor(tm, 16, 64));                                \
        tm = fmaxf(tm, __shfl_xor(tm, 32, 64));                                \
        const bool nresc = __all(tm - m2 <= 8.0f);                             \
        const float mref = nresc ? m2 : fmaxf(m2, tm);                         \
        _Pragma("unroll")                                                      \
        for (int s_ = 0; s_ < 2; ++s_)                                         \
            _Pragma("unroll")                                                  \
            for (int r = 0; r < 4; ++r) {                                      \
                pf0[s_ * 4 + r] = (nbf16)exp2f(st[s_][r] - mref);              \
                pf1[s_ * 4 + r] = (nbf16)exp2f(st[2 + s_][r] - mref);          \
            }                                                                  \
        if (!nresc) {                                                          \
            const float alpha = exp2f(m2 - mref);                              \
            m2 = mref;                                                         \
            float av[4];                                                       \
            _Pragma("unroll")                                                  \
            for (int r = 0; r < 4; ++r) av[r] = __shfl(alpha, lg * 4 + r, 64); \
            _Pragma("unroll")                                                  \
            for (int i = 0; i < 4; ++i)                                        \
                _Pragma("unroll")                                              \
                for (int r = 0; r < 4; ++r) o[i][r] *= av[r];                  \
            _Pragma("unroll")                                                  \
            for (int r = 0; r < 4; ++r) osum[r] *= av[r];                      \
        }                                                                      \
    } while (0)

    float m2A = -3.0e38f, m2B = -3.0e38f;
    f32x4 oA[4], oB[4], osumA, osumB;
    #pragma unroll
    for (int i = 0; i < 4; ++i) { oA[i] = (f32x4){0,0,0,0}; oB[i] = (f32x4){0,0,0,0}; }
    osumA = (f32x4){0, 0, 0, 0};
    osumB = (f32x4){0, 0, 0, 0};

    const int NT = SPLIT ? (SEQ / 2) / 64 : SEQ / 64;

    {   // prologue: stage K tile 0 (DMA) + V tile 0
        uint4 a0, a1;
        STAGEK(0, 0);
        VLOAD(0);
        VWRITE(0);
    }
    __syncthreads();

    for (int t = 0; t < NT; ++t) {
        const int cur = t & 1;
        uint4 a0, a1;
        if (t + 1 < NT) {
            STAGEK(cur ^ 1, t + 1);
            VLOAD(t + 1);
        }

        // ---- QK^T from KL[cur] ----
        f32x4 stA[4], stB[4];
        __builtin_amdgcn_s_setprio(1);
        #pragma unroll
        for (int sub = 0; sub < 4; ++sub) {
            const int row = sub * 16 + l15;
            const int s0 = lg ^ (row & 7);
            const int s1 = (4 + lg) ^ (row & 7);
            const bf16x8 kf0 = *(const bf16x8*)((const nbf16*)&KL[cur][row][0] + s0 * 8);
            const bf16x8 kf1 = *(const bf16x8*)((const nbf16*)&KL[cur][row][0] + s1 * 8);
            f32x4 a = (f32x4){0,0,0,0};
            a = __builtin_amdgcn_mfma_f32_16x16x32_bf16(kf0, qfA0, a, 0, 0, 0);
            a = __builtin_amdgcn_mfma_f32_16x16x32_bf16(kf1, qfA1, a, 0, 0, 0);
            stA[sub] = a;
            f32x4 b = (f32x4){0,0,0,0};
            b = __builtin_amdgcn_mfma_f32_16x16x32_bf16(kf0, qfB0, b, 0, 0, 0);
            b = __builtin_amdgcn_mfma_f32_16x16x32_bf16(kf1, qfB1, b, 0, 0, 0);
            stB[sub] = b;
        }
        __builtin_amdgcn_s_setprio(0);

        bf16x8 pfA0, pfA1, pfB0, pfB1;
        SOFTMAX(stA, m2A, oA, osumA, pfA0, pfA1);
        SOFTMAX(stB, m2B, oB, osumB, pfB0, pfB1);

        // ---- PV + denominator MFMA (P direct from registers) ----
        __builtin_amdgcn_s_setprio(1);
        #pragma unroll
        for (int db = 0; db < 4; ++db) {
            const nbf16* vr = &VT[cur][db * 16 + l15][0];
            const bf16x8 vf0 = *(const bf16x8*)(vr + swz0);
            const bf16x8 vf1 = *(const bf16x8*)(vr + swz1);
            oA[db] = __builtin_amdgcn_mfma_f32_16x16x32_bf16(pfA0, vf0, oA[db], 0, 0, 0);
            oA[db] = __builtin_amdgcn_mfma_f32_16x16x32_bf16(pfA1, vf1, oA[db], 0, 0, 0);
            oB[db] = __builtin_amdgcn_mfma_f32_16x16x32_bf16(pfB0, vf0, oB[db], 0, 0, 0);
            oB[db] = __builtin_amdgcn_mfma_f32_16x16x32_bf16(pfB1, vf1, oB[db], 0, 0, 0);
        }
        osumA = __builtin_amdgcn_mfma_f32_16x16x32_bf16(pfA0, ones, osumA, 0, 0, 0);
        osumA = __builtin_amdgcn_mfma_f32_16x16x32_bf16(pfA1, ones, osumA, 0, 0, 0);
        osumB = __builtin_amdgcn_mfma_f32_16x16x32_bf16(pfB0, ones, osumB, 0, 0, 0);
        osumB = __builtin_amdgcn_mfma_f32_16x16x32_bf16(pfB1, ones, osumB, 0, 0, 0);
        __builtin_amdgcn_s_setprio(0);

        if (t + 1 < NT) VWRITE(cur ^ 1);
        __syncthreads();
    }

    if (!SPLIT) {
        const int b = bh >> 4, h = bh & 15;
        #pragma unroll
        for (int db = 0; db < 4; ++db) {
            #pragma unroll
            for (int r = 0; r < 4; ++r) {
                const int qA = qbase + lg * 4 + r;
                cg[((size_t)(b * SEQ + qA)) * D_MODEL + h * HDK + db * 16 + l15] =
                    (nbf16)(oA[db][r] / osumA[r]);
                const int qB_ = qbase + 16 + lg * 4 + r;
                cg[((size_t)(b * SEQ + qB_)) * D_MODEL + h * HDK + db * 16 + l15] =
                    (nbf16)(oB[db][r] / osumB[r]);
            }
        }
    } else {
        float mvA[4], mvB[4];
        #pragma unroll
        for (int r = 0; r < 4; ++r) {
            mvA[r] = __shfl(m2A, lg * 4 + r, 64);
            mvB[r] = __shfl(m2B, lg * 4 + r, 64);
        }
        const int p = (bh * 16 + qt) * 2 + half;
        float* po = part_o + (size_t)p * (128 * 64);
        #pragma unroll
        for (int db = 0; db < 4; ++db) {
            #pragma unroll
            for (int r = 0; r < 4; ++r) {
                po[(wid * 32 + lg * 4 + r) * 64 + db * 16 + l15]      = oA[db][r];
                po[(wid * 32 + 16 + lg * 4 + r) * 64 + db * 16 + l15] = oB[db][r];
            }
        }
        if (l15 == 0) {
            #pragma unroll
            for (int r = 0; r < 4; ++r) {
                part_ms[(size_t)p * 128 + wid * 32 + lg * 4 + r]      =
                    make_float2(mvA[r], osumA[r]);
                part_ms[(size_t)p * 128 + wid * 32 + 16 + lg * 4 + r] =
                    make_float2(mvB[r], osumB[r]);
            }
        }
    }
    #undef STAGEK
    #undef VLOAD
    #undef VWRITE
    #undef SOFTMAX
}

// ---------------------------------------------------------------------------
// Combine the two kv-half partials (proven round 11).
// ---------------------------------------------------------------------------
__global__ void attn_combine(const float* __restrict__ part_o,
                             const float2* __restrict__ part_ms,
                             nbf16* __restrict__ cg) {
    const int bq = blockIdx.x;           // bh*16 + qt
    const int bh = bq >> 4, qt = bq & 15;
    const int p0 = bq * 2, p1 = bq * 2 + 1;
    const int q  = threadIdx.x >> 1;     // 0..127
    const int d0 = (threadIdx.x & 1) * 32;

    const float2 s1 = part_ms[(size_t)p0 * 128 + q];
    const float2 s2 = part_ms[(size_t)p1 * 128 + q];
    const float m  = fmaxf(s1.x, s2.x);
    const float w1 = exp2f(s1.x - m);
    const float w2 = exp2f(s2.x - m);
    const float inv = 1.f / (s1.y * w1 + s2.y * w2);

    const float* o1 = part_o + (size_t)p0 * (128 * 64) + q * 64 + d0;
    const float* o2 = part_o + (size_t)p1 * (128 * 64) + q * 64 + d0;
    const int b = bh >> 4, h = bh & 15;
    nbf16* out = cg + ((size_t)(b * SEQ + qt * 128 + q)) * D_MODEL + h * HDK + d0;
    #pragma unroll
    for (int j = 0; j < 8; ++j) {
        const float4 a = *(const float4*)(o1 + j * 4);
        const float4 c = *(const float4*)(o2 + j * 4);
        out[j * 4 + 0] = (nbf16)((a.x * w1 + c.x * w2) * inv);
        out[j * 4 + 1] = (nbf16)((a.y * w1 + c.y * w2) * inv);
        out[j * 4 + 2] = (nbf16)((a.z * w1 + c.z * w2) * inv);
        out[j * 4 + 3] = (nbf16)((a.w * w1 + c.w * w2) * inv);
    }
}

// ---------------------------------------------------------------------------
extern "C" void kernel_launch(void* const* d_in, const int* in_sizes, int n_in,
                              void* d_out, int out_size, void* d_ws, size_t ws_size,
                              hipStream_t stream) {
    const void* X  = d_in[0];
    const void* Y  = d_in[1];
    const void* qW = d_in[2];
    const void* qB = d_in[3];
    const void* kW = d_in[4];
    const void* kB = d_in[5];
    const void* vW = d_in[6];
    const void* vB = d_in[7];
    const void* oW = d_in[8];
    const void* oB = d_in[9];

    // ---- workspace layout (proven 56MB base; split partials only if room) ----
    nbf16* ws = (nbf16*)d_ws;
    nbf16* qbuf = ws;
    nbf16* kbuf = qbuf + QSZ;
    nbf16* vbuf = kbuf + QSZ;
    nbf16* cbuf = vbuf + QSZ;
    nbf16* Xb   = cbuf + QSZ;
    nbf16* Yb   = Xb + QSZ;
    nbf16* Wt3  = Yb + QSZ;
    nbf16* Wto  = Wt3 + 3 * WSZ;
    int*   flag = (int*)(Wto + WSZ);
    char*  pbase = (char*)flag + 256;
    float2* part_ms = (float2*)pbase;                          // 1 MB
    float*  part_o  = (float*)(part_ms + (size_t)1024 * 128);  // 32 MB
    const size_t need_split =
        (size_t)((char*)(part_o + (size_t)1024 * 128 * 64) - (char*)d_ws);
    const bool use_split = (ws_size >= need_split);

    detect_dtype<<<1, 256, 0, stream>>>((const unsigned short*)X, flag);

    prep<<<5120, 256, 0, stream>>>(X, Y, qW, kW, vW, oW, Xb, Yb, Wt3, Wto, flag);

    proj_qkv<<<768, 256, 0, stream>>>(Xb, Yb, Wt3, qB, kB, vB, qbuf, flag);

    if (use_split) {
        attn_mfma<true><<<1024, 256, 0, stream>>>(qbuf, kbuf, vbuf, cbuf,
                                                  part_o, part_ms);
        attn_combine<<<512, 256, 0, stream>>>(part_o, part_ms, cbuf);
    } else {
        attn_mfma<false><<<512, 256, 0, stream>>>(qbuf, kbuf, vbuf, cbuf,
                                                  nullptr, nullptr);
    }

    proj_o<<<256, 256, 0, stream>>>(cbuf, Wto, oB, d_out, flag);
}